// Round 2
// baseline (97.814 us; speedup 1.0000x reference)
//
#include <hip/hip_runtime.h>
#include <hip/hip_bf16.h>

// Problem: B=512, D=256, M=256, TEMP=0.07
//   anchor = features_o[mask_sents]            [M,D]
//   sim    = anchor @ features_i^T / TEMP      [M,B]
//   loss_sum = sum_m sum_{p in pos(m)} sum_{n in neg(m)} softplus(sim[m,n]-sim[m,p])
//   pair_num = sum_m |pos(m)|*|neg(m)|
//   loss = pair_num>0 ? loss_sum/pair_num : loss_sum
//
// Fully fused: one block per row m (256 blocks x 512 threads).
// d_ws usage: [0] float loss_sum, [1] uint pair_num, [2] uint block ticket.

#define BDIM 512
#define MDIM 256
#define DDIM 256
#define INV_TEMP (1.0f / 0.07f)

__global__ __launch_bounds__(512) void fused_loss_kernel(
        const float* __restrict__ fo, const float* __restrict__ fi,
        const float* __restrict__ mask, const int* __restrict__ sents,
        float* __restrict__ ws, float* __restrict__ out) {
    __shared__ float s_anchor[DDIM];
    __shared__ float s_psim[BDIM];
    __shared__ float s_nsim[BDIM];
    __shared__ int   s_wcnt[8];
    __shared__ float s_red[8];

    const int tid  = threadIdx.x;
    const int lane = tid & 63;
    const int wave = tid >> 6;
    const int m    = blockIdx.x;
    const int srow = sents[m];

    // stage anchor row (coalesced, 1 KB)
    if (tid < DDIM) s_anchor[tid] = fo[srow * DDIM + tid];
    const float mv = mask[srow * BDIM + tid];
    __syncthreads();

    // ---- sim[m, tid] = dot(anchor, fi[tid]) / TEMP --------------------------
    // per-lane row read, float4-vectorized; fi is 512 KB -> L2-resident
    const float4* bf = (const float4*)(fi + (size_t)tid * DDIM);
    const float4* af = (const float4*)s_anchor;   // broadcast reads (free)
    float acc0 = 0.f, acc1 = 0.f;
#pragma unroll 8
    for (int k = 0; k < DDIM / 8; ++k) {
        float4 b0 = bf[2 * k], b1 = bf[2 * k + 1];
        float4 a0 = af[2 * k], a1 = af[2 * k + 1];
        acc0 = fmaf(a0.x, b0.x, acc0); acc0 = fmaf(a0.y, b0.y, acc0);
        acc0 = fmaf(a0.z, b0.z, acc0); acc0 = fmaf(a0.w, b0.w, acc0);
        acc1 = fmaf(a1.x, b1.x, acc1); acc1 = fmaf(a1.y, b1.y, acc1);
        acc1 = fmaf(a1.z, b1.z, acc1); acc1 = fmaf(a1.w, b1.w, acc1);
    }
    const float simval = (acc0 + acc1) * INV_TEMP;

    // ---- deterministic ballot-based pos/neg compaction ----------------------
    const bool flag = (mv > 0.5f);
    unsigned long long bal = __ballot(flag);
    int below = __popcll(bal & ((1ull << lane) - 1ull));
    if (lane == 0) s_wcnt[wave] = __popcll(bal);
    __syncthreads();
    int base_pos = 0, np = 0;
#pragma unroll
    for (int w = 0; w < 8; ++w) {
        int c = s_wcnt[w];
        if (w < wave) base_pos += c;
        np += c;
    }
    const int nn = BDIM - np;
    const int base_neg = wave * 64 - base_pos;
    if (flag) s_psim[base_pos + below]          = simval;
    else      s_nsim[base_neg + (lane - below)] = simval;
    __syncthreads();

    // ---- pair loop: virtual 32(n) x 16(p) grid ------------------------------
    const int tn = tid & 31;
    const int tp = tid >> 5;          // 0..15
    float lsum = 0.f;
    for (int jp = tp; jp < np; jp += 16) {
        const float sp = s_psim[jp];                  // broadcast
        for (int jn = tn; jn < nn; jn += 32) {
            float x = s_nsim[jn] - sp;                // sim_n - sim_p
            float e = __expf(-fabsf(x));
            lsum += fmaxf(x, 0.f) + __logf(1.f + e);  // stable softplus
        }
    }

    // ---- block reduction + global accumulate --------------------------------
#pragma unroll
    for (int off = 32; off > 0; off >>= 1) lsum += __shfl_down(lsum, off);
    if (lane == 0) s_red[wave] = lsum;
    __syncthreads();
    if (tid == 0) {
        float bs = 0.f;
#pragma unroll
        for (int w = 0; w < 8; ++w) bs += s_red[w];
        atomicAdd(&ws[0], bs);
        atomicAdd((unsigned int*)ws + 1, (unsigned int)(np * nn));
        __threadfence();
        unsigned int old = atomicAdd((unsigned int*)ws + 2, 1u);
        if (old == (unsigned int)(gridDim.x - 1)) {
            // last block finalizes (agent-scope loads see all prior atomics)
            __threadfence();
            float ls = __hip_atomic_load(&ws[0], __ATOMIC_RELAXED,
                                         __HIP_MEMORY_SCOPE_AGENT);
            unsigned int pn = __hip_atomic_load((unsigned int*)ws + 1,
                                                __ATOMIC_RELAXED,
                                                __HIP_MEMORY_SCOPE_AGENT);
            out[0] = (pn > 0u) ? (ls / (float)pn) : ls;
        }
    }
}

extern "C" void kernel_launch(void* const* d_in, const int* in_sizes, int n_in,
                              void* d_out, int out_size, void* d_ws, size_t ws_size,
                              hipStream_t stream) {
    const float* fo    = (const float*)d_in[0];   // [512,256]
    const float* fi    = (const float*)d_in[1];   // [512,256]
    const float* mask  = (const float*)d_in[2];   // [512,512]
    const int*   sents = (const int*)d_in[3];     // [256]
    float* out = (float*)d_out;
    float* ws  = (float*)d_ws;

    // zero the three accumulators (ws is re-poisoned before every launch)
    hipMemsetAsync(d_ws, 0, 12, stream);

    fused_loss_kernel<<<MDIM, BDIM, 0, stream>>>(fo, fi, mask, sents, ws, out);
}